// Round 5
// baseline (100.880 us; speedup 1.0000x reference)
//
#include <hip/hip_runtime.h>
#include <stdint.h>

// Expansion + checkerboard-preserving dropout.
// Phase 1: pack FINAL mask bits ((rand>0.25 | center) & in-bounds) into 3200 u32.
// Phase 2: per block (half-image), stage contiguous x rows + mask words into LDS
//          via global_load_lds(16B); inner loop has no bounds logic; nt stores.

#define KEEP_SCALE (1.0f / 0.75f)

typedef float f32x4 __attribute__((ext_vector_type(4)));

__global__ __launch_bounds__(256) void build_mask_kernel(
    const float* __restrict__ rv,       // (320,320)
    uint32_t* __restrict__ mask)        // 3200 words, 10 per row
{
    int w = blockIdx.x * 256 + threadIdx.x;
    if (w >= 3200) return;
    int oh  = w / 10;
    int ow0 = (w - oh * 10) * 32;
    int qh = oh / 5, rh = oh - qh * 5;
    int ih = qh + rh - 2;
    bool hok = ((unsigned)ih < 64u);
    bool hc  = (rh == 2);
    const float* rp = rv + oh * 320 + ow0;
    uint32_t m = 0;
    #pragma unroll
    for (int b = 0; b < 32; ++b) {
        int ow = ow0 + b;
        int q = ow / 5, r = ow - q * 5;
        int iw = q + r - 2;
        bool keep = ((rp[b] > 0.25f) || (hc && (r == 2)))
                    && hok && ((unsigned)iw < 64u);
        m |= (uint32_t)keep << b;
    }
    mask[w] = m;
}

__global__ __launch_bounds__(320) void expand_cps_dropout_kernel(
    const float* __restrict__ x,        // (1024, 64, 64)
    const uint32_t* __restrict__ mask,  // 3200 words (bounds folded in)
    float* __restrict__ out)            // (1024, 320, 320)
{
    __shared__ float    xs[34 * 64];    // 8704 B: source rows [r0, r0+34), unpadded
    __shared__ uint32_t ms[1600];       // 6400 B: mask words for this half

    const int t    = threadIdx.x;       // 0..319
    const int half = blockIdx.x;        // 0: out rows 0..159, 1: rows 160..319
    const int bc   = blockIdx.y;        // 0..1023
    const int r0   = half ? 30 : 0;     // first staged source row

    // ---- stage: straight contiguous copies, direct global->LDS ----
    const float* xsrc = x + (size_t)bc * 4096 + r0 * 64;   // 8704 B region
    for (int i = t; i < 544; i += 320) {                   // 544 x 16B chunks
        __builtin_amdgcn_global_load_lds(
            (const __attribute__((address_space(1))) void*)(xsrc + i * 4),
            (__attribute__((address_space(3))) void*)(xs + (i & ~63) * 4),
            16, 0, 0);
    }
    const uint32_t* msrc = mask + half * 1600;             // 6400 B region
    for (int i = t; i < 400; i += 320) {                   // 400 x 16B chunks
        __builtin_amdgcn_global_load_lds(
            (const __attribute__((address_space(1))) void*)(msrc + i * 4),
            (__attribute__((address_space(3))) void*)(ms + (i & ~63) * 4),
            16, 0, 0);
    }
    __syncthreads();   // drains vmcnt before barrier

    // ---- per-thread column pattern (fixed) ----
    const int ow4 = t % 80;
    const int ohL = t / 80;             // 0..3
    const int ow  = ow4 * 4;

    int xoffb[4];                       // byte offset within a staged row
    #pragma unroll
    for (int k = 0; k < 4; ++k) {
        int o = ow + k;
        int q = o / 5, r = o - q * 5;
        int iw = q + r - 2;
        iw = iw < 0 ? 0 : (iw > 63 ? 63 : iw);   // safe read; mask kills OOB
        xoffb[k] = iw * 4;
    }
    const int msh = (ow4 & 7) * 4;
    const uint32_t* msp = ms + ohL * 10 + (ow4 >> 3);   // +j*40 words per row step
    const char* xsb = (const char*)xs;

    float* op = out + (size_t)bc * 102400 + (size_t)(half * 160 + ohL) * 320 + ow;
    const int ohbase = half * 160 + ohL;

    #pragma unroll 8
    for (int j = 0; j < 40; ++j) {
        int oh = ohbase + 4 * j;
        int q = oh / 5, r = oh - q * 5;
        int ih = q + r - 2;
        ih = ih < 0 ? 0 : (ih > 63 ? 63 : ih);   // clamp; mask kills OOB
        const char* xr = xsb + (ih - r0) * 256;  // staged row, 0..33
        uint32_t mb = msp[j * 40] >> msh;

        f32x4 o;
        o.x = (mb & 1u) ? *(const float*)(xr + xoffb[0]) * KEEP_SCALE : 0.0f;
        o.y = (mb & 2u) ? *(const float*)(xr + xoffb[1]) * KEEP_SCALE : 0.0f;
        o.z = (mb & 4u) ? *(const float*)(xr + xoffb[2]) * KEEP_SCALE : 0.0f;
        o.w = (mb & 8u) ? *(const float*)(xr + xoffb[3]) * KEEP_SCALE : 0.0f;
        __builtin_nontemporal_store(o, (f32x4*)(op + (size_t)(4 * j) * 320));
    }
}

extern "C" void kernel_launch(void* const* d_in, const int* in_sizes, int n_in,
                              void* d_out, int out_size, void* d_ws, size_t ws_size,
                              hipStream_t stream) {
    const float* x  = (const float*)d_in[0];
    const float* rv = (const float*)d_in[1];
    float* out      = (float*)d_out;
    uint32_t* mask  = (uint32_t*)d_ws;      // 12.8 KB

    hipLaunchKernelGGL(build_mask_kernel, dim3(13), dim3(256), 0, stream, rv, mask);

    dim3 block(320);
    dim3 grid(2, 1024);                     // (half, b*c)
    hipLaunchKernelGGL(expand_cps_dropout_kernel, grid, block, 0, stream,
                       x, mask, out);
}

// Round 6
// 91.660 us; speedup vs baseline: 1.1006x; 1.1006x over previous
//
#include <hip/hip_runtime.h>
#include <stdint.h>

// Expansion + checkerboard-preserving dropout.
// Phase 1: pack FINAL mask bits ((rand>0.25 | center) & in-bounds) into 3200 u32.
// Phase 2: per block (40 output rows of one image), stage 12 contiguous x rows +
//          400 mask words into LDS via global_load_lds(16B); inner loop has no
//          bounds logic (folded into mask); plain float4 stores.

#define KEEP_SCALE (1.0f / 0.75f)

typedef float f32x4 __attribute__((ext_vector_type(4)));

__global__ __launch_bounds__(256) void build_mask_kernel(
    const float* __restrict__ rv,       // (320,320)
    uint32_t* __restrict__ mask)        // 3200 words, 10 per row
{
    int w = blockIdx.x * 256 + threadIdx.x;
    if (w >= 3200) return;
    int oh  = w / 10;
    int ow0 = (w - oh * 10) * 32;
    int qh = oh / 5, rh = oh - qh * 5;
    int ih = qh + rh - 2;
    bool hok = ((unsigned)ih < 64u);
    bool hc  = (rh == 2);
    const float* rp = rv + oh * 320 + ow0;
    uint32_t m = 0;
    #pragma unroll
    for (int b = 0; b < 32; ++b) {
        int ow = ow0 + b;
        int q = ow / 5, r = ow - q * 5;
        int iw = q + r - 2;
        bool keep = ((rp[b] > 0.25f) || (hc && (r == 2)))
                    && hok && ((unsigned)iw < 64u);
        m |= (uint32_t)keep << b;
    }
    mask[w] = m;
}

__global__ __launch_bounds__(320) void expand_cps_dropout_kernel(
    const float* __restrict__ x,        // (1024, 64, 64)
    const uint32_t* __restrict__ mask,  // 3200 words (bounds folded in)
    float* __restrict__ out)            // (1024, 320, 320)
{
    __shared__ float    xs[12 * 64];    // 3072 B: source rows [s0, s0+12)
    __shared__ uint32_t ms[400];        // 1600 B: mask words for this 40-row group

    const int t  = threadIdx.x;         // 0..319
    const int g  = blockIdx.x;          // 0..7   (40-row group)
    const int bc = blockIdx.y;          // 0..1023

    int s0 = 8 * g - 2;                 // first staged source row, clamped
    s0 = s0 < 0 ? 0 : (s0 > 52 ? 52 : s0);

    // ---- stage (single pass, 292 chunks of 16B over 320 threads) ----
    if (t < 192) {                      // x: 12 rows * 256 B = 192 chunks
        const float* xsrc = x + (size_t)bc * 4096 + s0 * 64;
        __builtin_amdgcn_global_load_lds(
            (const __attribute__((address_space(1))) void*)(xsrc + t * 4),
            (__attribute__((address_space(3))) void*)(xs + (t & ~63) * 4),
            16, 0, 0);
    } else if (t < 292) {               // mask: 400 words = 100 chunks
        int i = t - 192;
        const uint32_t* msrc = mask + g * 400;
        __builtin_amdgcn_global_load_lds(
            (const __attribute__((address_space(1))) void*)(msrc + i * 4),
            (__attribute__((address_space(3))) void*)(ms + (i & ~63) * 4),
            16, 0, 0);
    }
    __syncthreads();   // drains vmcnt before barrier

    // ---- per-thread column pattern (fixed) ----
    const int ow4 = t % 80;
    const int ohL = t / 80;             // 0..3
    const int ow  = ow4 * 4;

    int xoffb[4];                       // byte offset within a staged row
    #pragma unroll
    for (int k = 0; k < 4; ++k) {
        int o = ow + k;
        int q = o / 5, r = o - q * 5;
        int iw = q + r - 2;
        iw = iw < 0 ? 0 : (iw > 63 ? 63 : iw);   // safe read; mask kills OOB
        xoffb[k] = iw * 4;
    }
    const int msh = (ow4 & 7) * 4;
    const uint32_t* msp = ms + ohL * 10 + (ow4 >> 3);   // +j*40 words per row step
    const char* xsb = (const char*)xs;

    const int ohbase = g * 40 + ohL;
    float* op = out + (size_t)bc * 102400 + (size_t)ohbase * 320 + ow;

    #pragma unroll
    for (int j = 0; j < 10; ++j) {
        int oh = ohbase + 4 * j;
        int q = oh / 5, r = oh - q * 5;
        int ih = q + r - 2;
        ih = ih < s0 ? s0 : (ih > s0 + 11 ? s0 + 11 : ih);  // clamp into staged range
        const char* xr = xsb + (ih - s0) * 256;
        uint32_t mb = msp[j * 40] >> msh;

        f32x4 o;
        o.x = (mb & 1u) ? *(const float*)(xr + xoffb[0]) * KEEP_SCALE : 0.0f;
        o.y = (mb & 2u) ? *(const float*)(xr + xoffb[1]) * KEEP_SCALE : 0.0f;
        o.z = (mb & 4u) ? *(const float*)(xr + xoffb[2]) * KEEP_SCALE : 0.0f;
        o.w = (mb & 8u) ? *(const float*)(xr + xoffb[3]) * KEEP_SCALE : 0.0f;
        *reinterpret_cast<f32x4*>(op + (size_t)(4 * j) * 320) = o;
    }
}

extern "C" void kernel_launch(void* const* d_in, const int* in_sizes, int n_in,
                              void* d_out, int out_size, void* d_ws, size_t ws_size,
                              hipStream_t stream) {
    const float* x  = (const float*)d_in[0];
    const float* rv = (const float*)d_in[1];
    float* out      = (float*)d_out;
    uint32_t* mask  = (uint32_t*)d_ws;      // 12.8 KB

    hipLaunchKernelGGL(build_mask_kernel, dim3(13), dim3(256), 0, stream, rv, mask);

    dim3 block(320);
    dim3 grid(8, 1024);                     // (row-group, b*c)
    hipLaunchKernelGGL(expand_cps_dropout_kernel, grid, block, 0, stream,
                       x, mask, out);
}